// Round 6
// baseline (343.386 us; speedup 1.0000x reference)
//
#include <hip/hip_runtime.h>
#include <hip/hip_cooperative_groups.h>

namespace cg = cooperative_groups;

#define D 512
#define DOUT 64
#define PREP_BLOCKS 256

typedef __bf16 bf16x8 __attribute__((ext_vector_type(8)));
typedef float floatx4 __attribute__((ext_vector_type(4)));

__device__ __forceinline__ void async_cp16(const void* g, void* lds) {
    __builtin_amdgcn_global_load_lds(
        (__attribute__((address_space(1))) void*)(void*)g,
        (__attribute__((address_space(3))) void*)lds, 16, 0, 0);
}

__device__ __forceinline__ void cvt8(const float* __restrict__ in,
                                     __bf16* __restrict__ out, int i) {
    const float4* p = (const float4*)in + (size_t)i * 2;
    float4 v0 = p[0], v1 = p[1];
    bf16x8 o;
    o[0] = (__bf16)v0.x; o[1] = (__bf16)v0.y; o[2] = (__bf16)v0.z; o[3] = (__bf16)v0.w;
    o[4] = (__bf16)v1.x; o[5] = (__bf16)v1.y; o[6] = (__bf16)v1.z; o[7] = (__bf16)v1.w;
    *((bf16x8*)out + i) = o;
}

// ---- cooperative prep: zero+cvt | degree | scan | offsets | fill — one dispatch ----
__global__ __launch_bounds__(256) void coop_prep(
        const int* __restrict__ src, const int* __restrict__ dst,
        int* __restrict__ deg, int* __restrict__ rp, int* __restrict__ cursor,
        int* __restrict__ col, int* __restrict__ bsum,
        const float* __restrict__ x, __bf16* __restrict__ xb, int xN8,
        const float* __restrict__ W1, __bf16* __restrict__ w1b, int w1N8,
        const float* __restrict__ W2, __bf16* __restrict__ w2b, int w2N8,
        int nN, int nE) {
    cg::grid_group grid = cg::this_grid();
    const int tid = threadIdx.x, b = blockIdx.x;
    const int lane = tid & 63, wid = tid >> 6;
    const int gidx = b * 256 + tid, gsz = gridDim.x * 256;

    // phase 0: zero deg + f32->bf16 conversions
    for (int i = gidx; i < nN; i += gsz) deg[i] = 0;
    for (int i = gidx; i < xN8; i += gsz) cvt8(x, xb, i);
    for (int i = gidx; i < w1N8; i += gsz) cvt8(W1, w1b, i);
    for (int i = gidx; i < w2N8; i += gsz) cvt8(W2, w2b, i);
    grid.sync();

    // phase 1: degree histogram
    for (int e = gidx; e < nE; e += gsz) atomicAdd(&deg[dst[e]], 1);
    grid.sync();

    // phase 2: per-block local exclusive scan of a 1024-elem chunk
    const int nChunks = (nN + 1023) >> 10;
    __shared__ int wtot[4];
    const int i4 = b * 1024 + tid * 4;
    if (b < nChunks) {
        int4 v = make_int4(0, 0, 0, 0);
        if (i4 + 3 < nN) v = *(const int4*)(deg + i4);
        else {
            if (i4 + 0 < nN) v.x = deg[i4 + 0];
            if (i4 + 1 < nN) v.y = deg[i4 + 1];
            if (i4 + 2 < nN) v.z = deg[i4 + 2];
        }
        int tsum = v.x + v.y + v.z + v.w;
        int s = tsum;
        #pragma unroll
        for (int off = 1; off < 64; off <<= 1) {
            int t = __shfl_up(s, off, 64);
            if (lane >= off) s += t;
        }
        if (lane == 63) wtot[wid] = s;
        __syncthreads();
        int woff = 0, btot = 0;
        #pragma unroll
        for (int i = 0; i < 4; ++i) {
            if (i < wid) woff += wtot[i];
            btot += wtot[i];
        }
        if (tid == 0) bsum[b] = btot;
        int excl = woff + (s - tsum);
        int4 o;
        o.x = excl; o.y = o.x + v.x; o.z = o.y + v.y; o.w = o.z + v.z;
        if (i4 + 3 < nN) *(int4*)(rp + i4) = o;
        else {
            if (i4 + 0 < nN) rp[i4 + 0] = o.x;
            if (i4 + 1 < nN) rp[i4 + 1] = o.y;
            if (i4 + 2 < nN) rp[i4 + 2] = o.z;
        }
    }
    grid.sync();

    // phase 3: block 0 scans chunk totals, writes grand total
    if (b == 0 && tid == 0) {
        int run = 0;
        for (int i = 0; i < nChunks; ++i) { int t = bsum[i]; bsum[i] = run; run += t; }
        rp[nN] = run;
    }
    grid.sync();

    // phase 4: add chunk offset; write cursor copy
    if (b < nChunks) {
        int add = bsum[b];
        #pragma unroll
        for (int j = 0; j < 4; ++j) {
            int i = i4 + j;
            if (i < nN) {
                int val = rp[i] + add;
                rp[i] = val;
                cursor[i] = val;
            }
        }
    }
    grid.sync();

    // phase 5: CSR fill
    for (int e = gidx; e < nE; e += gsz) {
        int d = dst[e];
        int p = atomicAdd(&cursor[d], 1);
        col[p] = src[e];
    }
}

// ---- bf16 MFMA NT GEMM (bf16 out) — m97-style ----
template<int BM, int BN, int WR, int WC, bool RELU>
__global__ __launch_bounds__(256) void gemm_mfma_nt(
        const __bf16* __restrict__ A, const __bf16* __restrict__ B,
        __bf16* __restrict__ Cout, int M, int N, int K) {
    constexpr int BK = 32;
    constexpr int WM = BM / WR, WN = BN / WC;
    constexpr int MI = WM / 16, NI = WN / 16;
    constexpr int CPA = BM / 64, CPB = BN / 64;

    __shared__ __bf16 As[4 * BM * 8];
    __shared__ __bf16 Bs[4 * BN * 8];

    const int tid = threadIdx.x;
    const int w = tid >> 6, lane = tid & 63;
    const int wrow = w / WC, wcol = w % WC;
    const int m0 = blockIdx.y * BM, n0 = blockIdx.x * BN;
    const int quad = lane >> 4, l15 = lane & 15;

    floatx4 acc[MI][NI] = {};

    for (int k0 = 0; k0 < K; k0 += BK) {
        #pragma unroll
        for (int c = 0; c < CPA; ++c) {
            int ca = w * CPA + c;
            int kq = ca / CPA;
            int row = m0 + (ca % CPA) * 64 + lane;
            if (row > M - 1) row = M - 1;
            async_cp16(A + (size_t)row * K + k0 + kq * 8, &As[(size_t)ca * 512]);
        }
        #pragma unroll
        for (int c = 0; c < CPB; ++c) {
            int cb = w * CPB + c;
            int kq = cb / CPB;
            int nn = n0 + (cb % CPB) * 64 + lane;
            async_cp16(B + (size_t)nn * K + k0 + kq * 8, &Bs[(size_t)cb * 512]);
        }
        __syncthreads();

        bf16x8 af[MI], bfr[NI];
        #pragma unroll
        for (int mi = 0; mi < MI; ++mi)
            af[mi] = *(const bf16x8*)&As[(size_t)(quad * BM + wrow * WM + mi * 16 + l15) * 8];
        #pragma unroll
        for (int nj = 0; nj < NI; ++nj)
            bfr[nj] = *(const bf16x8*)&Bs[(size_t)(quad * BN + wcol * WN + nj * 16 + l15) * 8];
        #pragma unroll
        for (int mi = 0; mi < MI; ++mi)
            #pragma unroll
            for (int nj = 0; nj < NI; ++nj)
                acc[mi][nj] = __builtin_amdgcn_mfma_f32_16x16x32_bf16(
                    af[mi], bfr[nj], acc[mi][nj], 0, 0, 0);
        __syncthreads();
    }

    #pragma unroll
    for (int mi = 0; mi < MI; ++mi) {
        #pragma unroll
        for (int r = 0; r < 4; ++r) {
            int m = m0 + wrow * WM + mi * 16 + quad * 4 + r;
            if (m < M) {
                #pragma unroll
                for (int nj = 0; nj < NI; ++nj) {
                    int n = n0 + wcol * WN + nj * 16 + l15;
                    float v = acc[mi][nj][r];
                    if (RELU) v = fmaxf(v, 0.f);
                    Cout[(size_t)m * N + n] = (__bf16)v;
                }
            }
        }
    }
}

// ---- fused: h2-rows = relu(S t) gathered into LDS, u = h2 @ W2^T (bf16 out) ----
// 32 nodes/block, 4 waves (wrow=w>>1, wcol=w&1). h2 never hits HBM.
__global__ __launch_bounds__(256) void prop1_gemm2(
        const __bf16* __restrict__ t, const int* __restrict__ rp,
        const int* __restrict__ col, const __bf16* __restrict__ B,
        __bf16* __restrict__ u, int nN) {
    __shared__ __bf16 As[32 * 512];    // 32KB: granule P = r*64 + ((lane+r)&63)
    __shared__ __bf16 Bs[4 * 64 * 8];  // 4KB chunk of W2: granule P = kq*64 + n

    const int tid = threadIdx.x;
    const int w = tid >> 6, lane = tid & 63;
    const int quad = lane >> 4, l15 = lane & 15;
    const int wrow = w >> 1, wcol = w & 1;
    const int m0 = blockIdx.x * 32;

    // gather phase: wave w handles local rows w, w+4, ..., w+28
    for (int r = w; r < 32; r += 4) {
        int n = m0 + r;
        float acc0[8] = {}, acc1[8] = {};
        if (n < nN) {
            int s0 = rp[n], s1 = rp[n + 1];
            int e = s0;
            for (; e + 4 <= s1; e += 4) {
                int sa = col[e], sb = col[e + 1], sc = col[e + 2], sd = col[e + 3];
                bf16x8 va = *(const bf16x8*)(t + (size_t)sa * D + lane * 8);
                bf16x8 vb = *(const bf16x8*)(t + (size_t)sb * D + lane * 8);
                bf16x8 vc = *(const bf16x8*)(t + (size_t)sc * D + lane * 8);
                bf16x8 vd = *(const bf16x8*)(t + (size_t)sd * D + lane * 8);
                #pragma unroll
                for (int i = 0; i < 8; ++i) {
                    acc0[i] += (float)va[i] + (float)vc[i];
                    acc1[i] += (float)vb[i] + (float)vd[i];
                }
            }
            for (; e < s1; ++e) {
                int sa = col[e];
                bf16x8 va = *(const bf16x8*)(t + (size_t)sa * D + lane * 8);
                #pragma unroll
                for (int i = 0; i < 8; ++i) acc0[i] += (float)va[i];
            }
        }
        bf16x8 o;
        #pragma unroll
        for (int i = 0; i < 8; ++i) o[i] = (__bf16)fmaxf(acc0[i] + acc1[i], 0.f);
        int P = r * 64 + ((lane + r) & 63);
        *(bf16x8*)&As[(size_t)P * 8] = o;
    }
    __syncthreads();

    // K-loop: stream W2 chunks, MFMA
    floatx4 acc[2] = {};
    for (int k0 = 0; k0 < D; k0 += 32) {
        async_cp16(B + (size_t)lane * D + k0 + w * 8, &Bs[(size_t)w * 512]);
        __syncthreads();
        int g = (k0 >> 3) + quad;
        int row = wrow * 16 + l15;
        bf16x8 af = *(const bf16x8*)&As[(size_t)(row * 64 + ((g + row) & 63)) * 8];
        #pragma unroll
        for (int nj = 0; nj < 2; ++nj) {
            bf16x8 bfr = *(const bf16x8*)&Bs[(size_t)(quad * 64 + wcol * 32 + nj * 16 + l15) * 8];
            acc[nj] = __builtin_amdgcn_mfma_f32_16x16x32_bf16(af, bfr, acc[nj], 0, 0, 0);
        }
        __syncthreads();
    }

    // write u rows (bf16)
    #pragma unroll
    for (int r = 0; r < 4; ++r) {
        int m = m0 + wrow * 16 + quad * 4 + r;
        if (m < nN) {
            #pragma unroll
            for (int nj = 0; nj < 2; ++nj)
                u[(size_t)m * DOUT + wcol * 32 + nj * 16 + l15] = (__bf16)acc[nj][r];
        }
    }
}

// ---- propagate 64-wide + log_softmax fused: wave per node, lane = output col ----
__global__ __launch_bounds__(256) void prop2_lsm(const __bf16* __restrict__ u,
        const int* __restrict__ rp, const int* __restrict__ col,
        float* __restrict__ out, int nN) {
    int n = blockIdx.x * 4 + (threadIdx.x >> 6);
    if (n >= nN) return;
    int lane = threadIdx.x & 63;
    int s0 = rp[n], s1 = rp[n + 1];
    float a0 = 0.f, a1 = 0.f, a2 = 0.f, a3 = 0.f;
    int e = s0;
    for (; e + 4 <= s1; e += 4) {
        int sa = col[e], sb = col[e + 1], sc = col[e + 2], sd = col[e + 3];
        a0 += (float)u[(size_t)sa * DOUT + lane];
        a1 += (float)u[(size_t)sb * DOUT + lane];
        a2 += (float)u[(size_t)sc * DOUT + lane];
        a3 += (float)u[(size_t)sd * DOUT + lane];
    }
    for (; e < s1; ++e) a0 += (float)u[(size_t)col[e] * DOUT + lane];
    float v = (a0 + a2) + (a1 + a3);
    float mx = v;
    #pragma unroll
    for (int off = 32; off >= 1; off >>= 1) mx = fmaxf(mx, __shfl_xor(mx, off, 64));
    float s = expf(v - mx);
    #pragma unroll
    for (int off = 32; off >= 1; off >>= 1) s += __shfl_xor(s, off, 64);
    out[(size_t)n * DOUT + lane] = v - mx - logf(s);
}

// ---------------- launch ----------------

extern "C" void kernel_launch(void* const* d_in, const int* in_sizes, int n_in,
                              void* d_out, int out_size, void* d_ws, size_t ws_size,
                              hipStream_t stream) {
    const float* x  = (const float*)d_in[0];
    const int*   ei = (const int*)d_in[1];
    const float* W1 = (const float*)d_in[2];
    const float* W2 = (const float*)d_in[3];
    float* out = (float*)d_out;

    int N = in_sizes[0] / D;   // 20000
    int E = in_sizes[1] / 2;   // 160000
    const int* src = ei;
    const int* dst = ei + E;

    size_t off = 0;
    auto alloc = [&](size_t bytes) -> void* {
        void* p = (char*)d_ws + off;
        off = (off + bytes + 255) & ~(size_t)255;
        return p;
    };
    int*    deg     = (int*)alloc(sizeof(int) * (size_t)N);
    int*    row_ptr = (int*)alloc(sizeof(int) * (size_t)(N + 1));
    int*    cursor  = (int*)alloc(sizeof(int) * (size_t)N);
    int*    col     = (int*)alloc(sizeof(int) * (size_t)E);
    int*    bsum    = (int*)alloc(sizeof(int) * 256);
    __bf16* w1b     = (__bf16*)alloc(sizeof(__bf16) * (size_t)D * D);
    __bf16* w2b     = (__bf16*)alloc(sizeof(__bf16) * (size_t)DOUT * D);
    __bf16* xb      = (__bf16*)alloc(sizeof(__bf16) * (size_t)N * D);
    __bf16* t       = (__bf16*)alloc(sizeof(__bf16) * (size_t)N * D);    // x@W1^T
    __bf16* u       = (__bf16*)alloc(sizeof(__bf16) * (size_t)N * DOUT); // relu(S t)@W2^T

    int xN8 = N * D / 8, w1N8 = D * D / 8, w2N8 = DOUT * D / 8;

    // 1) cooperative prep: zero+cvt | degree | scan | offsets | fill
    void* args[] = { (void*)&src, (void*)&dst, (void*)&deg, (void*)&row_ptr,
                     (void*)&cursor, (void*)&col, (void*)&bsum,
                     (void*)&x, (void*)&xb, (void*)&xN8,
                     (void*)&W1, (void*)&w1b, (void*)&w1N8,
                     (void*)&W2, (void*)&w2b, (void*)&w2N8,
                     (void*)&N, (void*)&E };
    hipLaunchCooperativeKernel((void*)coop_prep, dim3(PREP_BLOCKS), dim3(256),
                               args, 0, stream);

    // 2) t = x @ W1^T  (dense)
    dim3 g1(D / 128, (N + 127) / 128);
    gemm_mfma_nt<128, 128, 2, 2, false><<<g1, 256, 0, stream>>>(xb, w1b, t, N, D, D);
    // 3) u = relu(S t) @ W2^T  (fused gather + small GEMM; h2 never materialized)
    prop1_gemm2<<<(N + 31) / 32, 256, 0, stream>>>(t, row_ptr, col, w2b, u, N);
    // 4) out = lsm(S u)
    prop2_lsm<<<(N + 3) / 4, 256, 0, stream>>>(u, row_ptr, col, out, N);
}

// Round 7
// 186.041 us; speedup vs baseline: 1.8458x; 1.8458x over previous
//
#include <hip/hip_runtime.h>

#define D 512
#define DOUT 64

typedef __bf16 bf16x8 __attribute__((ext_vector_type(8)));
typedef float floatx4 __attribute__((ext_vector_type(4)));

__device__ __forceinline__ void async_cp16(const void* g, void* lds) {
    __builtin_amdgcn_global_load_lds(
        (__attribute__((address_space(1))) void*)(void*)g,
        (__attribute__((address_space(3))) void*)lds, 16, 0, 0);
}

// ---- fused: degree atomics + 3 f32->bf16 conversions, partitioned by blockIdx ----
__global__ __launch_bounds__(256) void misc_kernel(
        const int* __restrict__ dst, int* __restrict__ deg, int nE, int degBlocks,
        const float* __restrict__ x, __bf16* __restrict__ xb, int xN8,
        const float* __restrict__ W1, __bf16* __restrict__ w1b, int w1N8,
        const float* __restrict__ W2, __bf16* __restrict__ w2b, int w2N8) {
    int b = blockIdx.x;
    if (b < degBlocks) {
        int e = b * 256 + threadIdx.x;
        if (e < nE) atomicAdd(&deg[dst[e]], 1);
        return;
    }
    b -= degBlocks;
    int xBlocks = (xN8 + 255) >> 8;
    int w1Blocks = (w1N8 + 255) >> 8;
    const float* in; __bf16* outp; int n8;
    if (b < xBlocks) { in = x; outp = xb; n8 = xN8; }
    else if (b < xBlocks + w1Blocks) { b -= xBlocks; in = W1; outp = w1b; n8 = w1N8; }
    else { b -= xBlocks + w1Blocks; in = W2; outp = w2b; n8 = w2N8; }
    int i = b * 256 + threadIdx.x;
    if (i < n8) {
        const float4* p = (const float4*)in + (size_t)i * 2;
        float4 v0 = p[0], v1 = p[1];
        bf16x8 o;
        o[0] = (__bf16)v0.x; o[1] = (__bf16)v0.y; o[2] = (__bf16)v0.z; o[3] = (__bf16)v0.w;
        o[4] = (__bf16)v1.x; o[5] = (__bf16)v1.y; o[6] = (__bf16)v1.z; o[7] = (__bf16)v1.w;
        *((bf16x8*)outp + i) = o;
    }
}

// ---- single-block exclusive scan, 4 elems/thread; writes rp[0..n] and cursor ----
__global__ __launch_bounds__(1024) void exscan_kernel(const int* __restrict__ deg,
                                                      int* __restrict__ rp,
                                                      int* __restrict__ cursor, int n) {
    __shared__ int wtot[16];
    __shared__ int carry;
    int tid = threadIdx.x, lane = tid & 63, wid = tid >> 6;
    if (tid == 0) carry = 0;
    __syncthreads();
    for (int base = 0; base < n; base += 4096) {
        int i4 = base + tid * 4;
        int4 v = make_int4(0, 0, 0, 0);
        if (i4 + 3 < n) v = *(const int4*)(deg + i4);
        else {
            if (i4 + 0 < n) v.x = deg[i4 + 0];
            if (i4 + 1 < n) v.y = deg[i4 + 1];
            if (i4 + 2 < n) v.z = deg[i4 + 2];
            if (i4 + 3 < n) v.w = deg[i4 + 3];
        }
        int tsum = v.x + v.y + v.z + v.w;
        int s = tsum;
        #pragma unroll
        for (int off = 1; off < 64; off <<= 1) {
            int t = __shfl_up(s, off, 64);
            if (lane >= off) s += t;
        }
        if (lane == 63) wtot[wid] = s;
        __syncthreads();
        if (wid == 0 && lane < 16) {
            int wv = wtot[lane];
            int ws_ = wv;
            #pragma unroll
            for (int off = 1; off < 16; off <<= 1) {
                int t = __shfl_up(ws_, off, 64);
                if (lane >= off) ws_ += t;
            }
            wtot[lane] = ws_ - wv;
        }
        __syncthreads();
        int excl = carry + wtot[wid] + (s - tsum);
        int4 o;
        o.x = excl; o.y = o.x + v.x; o.z = o.y + v.y; o.w = o.z + v.z;
        if (i4 + 3 < n) {
            *(int4*)(rp + i4) = o;
            *(int4*)(cursor + i4) = o;
        } else {
            if (i4 + 0 < n) { rp[i4 + 0] = o.x; cursor[i4 + 0] = o.x; }
            if (i4 + 1 < n) { rp[i4 + 1] = o.y; cursor[i4 + 1] = o.y; }
            if (i4 + 2 < n) { rp[i4 + 2] = o.z; cursor[i4 + 2] = o.z; }
            if (i4 + 3 < n) { rp[i4 + 3] = o.w; cursor[i4 + 3] = o.w; }
        }
        __syncthreads();
        if (tid == 1023) carry = o.w + v.w;
        __syncthreads();
    }
    if (tid == 0) rp[n] = carry;
}

__global__ void fill_kernel(const int* __restrict__ src, const int* __restrict__ dst,
                            int* __restrict__ cursor, int* __restrict__ col, int nE) {
    int e = blockIdx.x * blockDim.x + threadIdx.x;
    if (e < nE) {
        int d = dst[e];
        int p = atomicAdd(&cursor[d], 1);
        col[p] = src[e];
    }
}

// ---- bf16 MFMA NT GEMM (bf16 out) — m97-style ----
template<int BM, int BN, int WR, int WC, bool RELU>
__global__ __launch_bounds__(256) void gemm_mfma_nt(
        const __bf16* __restrict__ A, const __bf16* __restrict__ B,
        __bf16* __restrict__ Cout, int M, int N, int K) {
    constexpr int BK = 32;
    constexpr int WM = BM / WR, WN = BN / WC;
    constexpr int MI = WM / 16, NI = WN / 16;
    constexpr int CPA = BM / 64, CPB = BN / 64;

    __shared__ __bf16 As[4 * BM * 8];
    __shared__ __bf16 Bs[4 * BN * 8];

    const int tid = threadIdx.x;
    const int w = tid >> 6, lane = tid & 63;
    const int wrow = w / WC, wcol = w % WC;
    const int m0 = blockIdx.y * BM, n0 = blockIdx.x * BN;
    const int quad = lane >> 4, l15 = lane & 15;

    floatx4 acc[MI][NI] = {};

    for (int k0 = 0; k0 < K; k0 += BK) {
        #pragma unroll
        for (int c = 0; c < CPA; ++c) {
            int ca = w * CPA + c;
            int kq = ca / CPA;
            int row = m0 + (ca % CPA) * 64 + lane;
            if (row > M - 1) row = M - 1;
            async_cp16(A + (size_t)row * K + k0 + kq * 8, &As[(size_t)ca * 512]);
        }
        #pragma unroll
        for (int c = 0; c < CPB; ++c) {
            int cb = w * CPB + c;
            int kq = cb / CPB;
            int nn = n0 + (cb % CPB) * 64 + lane;
            async_cp16(B + (size_t)nn * K + k0 + kq * 8, &Bs[(size_t)cb * 512]);
        }
        __syncthreads();

        bf16x8 af[MI], bfr[NI];
        #pragma unroll
        for (int mi = 0; mi < MI; ++mi)
            af[mi] = *(const bf16x8*)&As[(size_t)(quad * BM + wrow * WM + mi * 16 + l15) * 8];
        #pragma unroll
        for (int nj = 0; nj < NI; ++nj)
            bfr[nj] = *(const bf16x8*)&Bs[(size_t)(quad * BN + wcol * WN + nj * 16 + l15) * 8];
        #pragma unroll
        for (int mi = 0; mi < MI; ++mi)
            #pragma unroll
            for (int nj = 0; nj < NI; ++nj)
                acc[mi][nj] = __builtin_amdgcn_mfma_f32_16x16x32_bf16(
                    af[mi], bfr[nj], acc[mi][nj], 0, 0, 0);
        __syncthreads();
    }

    #pragma unroll
    for (int mi = 0; mi < MI; ++mi) {
        #pragma unroll
        for (int r = 0; r < 4; ++r) {
            int m = m0 + wrow * WM + mi * 16 + quad * 4 + r;
            if (m < M) {
                #pragma unroll
                for (int nj = 0; nj < NI; ++nj) {
                    int n = n0 + wcol * WN + nj * 16 + l15;
                    float v = acc[mi][nj][r];
                    if (RELU) v = fmaxf(v, 0.f);
                    Cout[(size_t)m * N + n] = (__bf16)v;
                }
            }
        }
    }
}

// ---- fused: h2-rows = relu(S t) gathered into LDS, u = h2 @ W2^T (bf16 out) ----
// 32 nodes/block, 4 waves (wrow=w>>1, wcol=w&1). h2 never hits HBM.
__global__ __launch_bounds__(256) void prop1_gemm2(
        const __bf16* __restrict__ t, const int* __restrict__ rp,
        const int* __restrict__ col, const __bf16* __restrict__ B,
        __bf16* __restrict__ u, int nN) {
    __shared__ __bf16 As[32 * 512];    // 32KB: granule P = r*64 + ((lane+r)&63)
    __shared__ __bf16 Bs[4 * 64 * 8];  // 4KB chunk of W2: granule P = kq*64 + n

    const int tid = threadIdx.x;
    const int w = tid >> 6, lane = tid & 63;
    const int quad = lane >> 4, l15 = lane & 15;
    const int wrow = w >> 1, wcol = w & 1;
    const int m0 = blockIdx.x * 32;

    // gather phase: wave w handles local rows w, w+4, ..., w+28
    for (int r = w; r < 32; r += 4) {
        int n = m0 + r;
        float acc0[8] = {}, acc1[8] = {};
        if (n < nN) {
            int s0 = rp[n], s1 = rp[n + 1];
            int e = s0;
            for (; e + 4 <= s1; e += 4) {
                int sa = col[e], sb = col[e + 1], sc = col[e + 2], sd = col[e + 3];
                bf16x8 va = *(const bf16x8*)(t + (size_t)sa * D + lane * 8);
                bf16x8 vb = *(const bf16x8*)(t + (size_t)sb * D + lane * 8);
                bf16x8 vc = *(const bf16x8*)(t + (size_t)sc * D + lane * 8);
                bf16x8 vd = *(const bf16x8*)(t + (size_t)sd * D + lane * 8);
                #pragma unroll
                for (int i = 0; i < 8; ++i) {
                    acc0[i] += (float)va[i] + (float)vc[i];
                    acc1[i] += (float)vb[i] + (float)vd[i];
                }
            }
            for (; e < s1; ++e) {
                int sa = col[e];
                bf16x8 va = *(const bf16x8*)(t + (size_t)sa * D + lane * 8);
                #pragma unroll
                for (int i = 0; i < 8; ++i) acc0[i] += (float)va[i];
            }
        }
        bf16x8 o;
        #pragma unroll
        for (int i = 0; i < 8; ++i) o[i] = (__bf16)fmaxf(acc0[i] + acc1[i], 0.f);
        int P = r * 64 + ((lane + r) & 63);
        *(bf16x8*)&As[(size_t)P * 8] = o;
    }
    __syncthreads();

    // K-loop: stream W2 chunks, MFMA
    floatx4 acc[2] = {};
    for (int k0 = 0; k0 < D; k0 += 32) {
        async_cp16(B + (size_t)lane * D + k0 + w * 8, &Bs[(size_t)w * 512]);
        __syncthreads();
        int g = (k0 >> 3) + quad;
        int row = wrow * 16 + l15;
        bf16x8 af = *(const bf16x8*)&As[(size_t)(row * 64 + ((g + row) & 63)) * 8];
        #pragma unroll
        for (int nj = 0; nj < 2; ++nj) {
            bf16x8 bfr = *(const bf16x8*)&Bs[(size_t)(quad * 64 + wcol * 32 + nj * 16 + l15) * 8];
            acc[nj] = __builtin_amdgcn_mfma_f32_16x16x32_bf16(af, bfr, acc[nj], 0, 0, 0);
        }
        __syncthreads();
    }

    // write u rows (bf16)
    #pragma unroll
    for (int r = 0; r < 4; ++r) {
        int m = m0 + wrow * 16 + quad * 4 + r;
        if (m < nN) {
            #pragma unroll
            for (int nj = 0; nj < 2; ++nj)
                u[(size_t)m * DOUT + wcol * 32 + nj * 16 + l15] = (__bf16)acc[nj][r];
        }
    }
}

// ---- propagate 64-wide + log_softmax fused: wave per node, lane = output col ----
__global__ __launch_bounds__(256) void prop2_lsm(const __bf16* __restrict__ u,
        const int* __restrict__ rp, const int* __restrict__ col,
        float* __restrict__ out, int nN) {
    int n = blockIdx.x * 4 + (threadIdx.x >> 6);
    if (n >= nN) return;
    int lane = threadIdx.x & 63;
    int s0 = rp[n], s1 = rp[n + 1];
    float a0 = 0.f, a1 = 0.f, a2 = 0.f, a3 = 0.f;
    int e = s0;
    for (; e + 4 <= s1; e += 4) {
        int sa = col[e], sb = col[e + 1], sc = col[e + 2], sd = col[e + 3];
        a0 += (float)u[(size_t)sa * DOUT + lane];
        a1 += (float)u[(size_t)sb * DOUT + lane];
        a2 += (float)u[(size_t)sc * DOUT + lane];
        a3 += (float)u[(size_t)sd * DOUT + lane];
    }
    for (; e < s1; ++e) a0 += (float)u[(size_t)col[e] * DOUT + lane];
    float v = (a0 + a2) + (a1 + a3);
    float mx = v;
    #pragma unroll
    for (int off = 32; off >= 1; off >>= 1) mx = fmaxf(mx, __shfl_xor(mx, off, 64));
    float s = expf(v - mx);
    #pragma unroll
    for (int off = 32; off >= 1; off >>= 1) s += __shfl_xor(s, off, 64);
    out[(size_t)n * DOUT + lane] = v - mx - logf(s);
}

// ---------------- launch ----------------

extern "C" void kernel_launch(void* const* d_in, const int* in_sizes, int n_in,
                              void* d_out, int out_size, void* d_ws, size_t ws_size,
                              hipStream_t stream) {
    const float* x  = (const float*)d_in[0];
    const int*   ei = (const int*)d_in[1];
    const float* W1 = (const float*)d_in[2];
    const float* W2 = (const float*)d_in[3];
    float* out = (float*)d_out;

    const int N = in_sizes[0] / D;   // 20000
    const int E = in_sizes[1] / 2;   // 160000
    const int* src = ei;
    const int* dst = ei + E;

    size_t off = 0;
    auto alloc = [&](size_t bytes) -> void* {
        void* p = (char*)d_ws + off;
        off = (off + bytes + 255) & ~(size_t)255;
        return p;
    };
    int*    deg     = (int*)alloc(sizeof(int) * (size_t)N);
    int*    row_ptr = (int*)alloc(sizeof(int) * (size_t)(N + 1));
    int*    cursor  = (int*)alloc(sizeof(int) * (size_t)N);
    int*    col     = (int*)alloc(sizeof(int) * (size_t)E);
    __bf16* w1b     = (__bf16*)alloc(sizeof(__bf16) * (size_t)D * D);
    __bf16* w2b     = (__bf16*)alloc(sizeof(__bf16) * (size_t)DOUT * D);
    __bf16* xb      = (__bf16*)alloc(sizeof(__bf16) * (size_t)N * D);
    __bf16* t       = (__bf16*)alloc(sizeof(__bf16) * (size_t)N * D);    // x@W1^T
    __bf16* u       = (__bf16*)alloc(sizeof(__bf16) * (size_t)N * DOUT); // relu(S t)@W2^T

    const int degBlocks = (E + 255) / 256;
    const int xN8 = N * D / 8, w1N8 = D * D / 8, w2N8 = DOUT * D / 8;
    const int cvtBlocks = (xN8 + 255) / 256 + (w1N8 + 255) / 256 + (w2N8 + 255) / 256;

    hipMemsetAsync(deg, 0, sizeof(int) * (size_t)N, stream);
    misc_kernel<<<degBlocks + cvtBlocks, 256, 0, stream>>>(
        dst, deg, E, degBlocks, x, xb, xN8, W1, w1b, w1N8, W2, w2b, w2N8);
    exscan_kernel<<<1, 1024, 0, stream>>>(deg, row_ptr, cursor, N);
    fill_kernel<<<(E + 255) / 256, 256, 0, stream>>>(src, dst, cursor, col, E);

    // t = x @ W1^T  (dense)
    dim3 g1(D / 128, (N + 127) / 128);
    gemm_mfma_nt<128, 128, 2, 2, false><<<g1, 256, 0, stream>>>(xb, w1b, t, N, D, D);
    // u = relu(S t) @ W2^T  (fused gather + small GEMM; h2 never materialized)
    prop1_gemm2<<<(N + 31) / 32, 256, 0, stream>>>(t, row_ptr, col, w2b, u, N);
    // out = lsm(S u)
    prop2_lsm<<<(N + 3) / 4, 256, 0, stream>>>(u, row_ptr, col, out, N);
}

// Round 8
// 175.721 us; speedup vs baseline: 1.9542x; 1.0587x over previous
//
#include <hip/hip_runtime.h>

#define D 512
#define DOUT 64

typedef __bf16 bf16x8 __attribute__((ext_vector_type(8)));
typedef float floatx4 __attribute__((ext_vector_type(4)));

__device__ __forceinline__ void async_cp16(const void* g, void* lds) {
    __builtin_amdgcn_global_load_lds(
        (__attribute__((address_space(1))) void*)(void*)g,
        (__attribute__((address_space(3))) void*)lds, 16, 0, 0);
}

// ---- prep: zero deg + 3 f32->bf16 conversions, partitioned by blockIdx ----
__global__ __launch_bounds__(256) void prep_kernel(
        int* __restrict__ deg, int nN, int zeroBlocks,
        const float* __restrict__ x, __bf16* __restrict__ xb, int xN8,
        const float* __restrict__ W1, __bf16* __restrict__ w1b, int w1N8,
        const float* __restrict__ W2, __bf16* __restrict__ w2b, int w2N8) {
    int b = blockIdx.x;
    if (b < zeroBlocks) {
        int i4 = b * 1024 + threadIdx.x * 4;
        if (i4 + 3 < nN) *(int4*)(deg + i4) = make_int4(0, 0, 0, 0);
        else {
            if (i4 + 0 < nN) deg[i4 + 0] = 0;
            if (i4 + 1 < nN) deg[i4 + 1] = 0;
            if (i4 + 2 < nN) deg[i4 + 2] = 0;
        }
        return;
    }
    b -= zeroBlocks;
    int xBlocks = (xN8 + 255) >> 8;
    int w1Blocks = (w1N8 + 255) >> 8;
    const float* in; __bf16* outp; int n8;
    if (b < xBlocks) { in = x; outp = xb; n8 = xN8; }
    else if (b < xBlocks + w1Blocks) { b -= xBlocks; in = W1; outp = w1b; n8 = w1N8; }
    else { b -= xBlocks + w1Blocks; in = W2; outp = w2b; n8 = w2N8; }
    int i = b * 256 + threadIdx.x;
    if (i < n8) {
        const float4* p = (const float4*)in + (size_t)i * 2;
        float4 v0 = p[0], v1 = p[1];
        bf16x8 o;
        o[0] = (__bf16)v0.x; o[1] = (__bf16)v0.y; o[2] = (__bf16)v0.z; o[3] = (__bf16)v0.w;
        o[4] = (__bf16)v1.x; o[5] = (__bf16)v1.y; o[6] = (__bf16)v1.z; o[7] = (__bf16)v1.w;
        *((bf16x8*)outp + i) = o;
    }
}

// ---- single-block exclusive scan, 4 elems/thread; writes rp[0..n] and cursor ----
__global__ __launch_bounds__(1024) void exscan_kernel(const int* __restrict__ deg,
                                                      int* __restrict__ rp,
                                                      int* __restrict__ cursor, int n) {
    __shared__ int wtot[16];
    __shared__ int carry;
    int tid = threadIdx.x, lane = tid & 63, wid = tid >> 6;
    if (tid == 0) carry = 0;
    __syncthreads();
    for (int base = 0; base < n; base += 4096) {
        int i4 = base + tid * 4;
        int4 v = make_int4(0, 0, 0, 0);
        if (i4 + 3 < n) v = *(const int4*)(deg + i4);
        else {
            if (i4 + 0 < n) v.x = deg[i4 + 0];
            if (i4 + 1 < n) v.y = deg[i4 + 1];
            if (i4 + 2 < n) v.z = deg[i4 + 2];
            if (i4 + 3 < n) v.w = deg[i4 + 3];
        }
        int tsum = v.x + v.y + v.z + v.w;
        int s = tsum;
        #pragma unroll
        for (int off = 1; off < 64; off <<= 1) {
            int t = __shfl_up(s, off, 64);
            if (lane >= off) s += t;
        }
        if (lane == 63) wtot[wid] = s;
        __syncthreads();
        if (wid == 0 && lane < 16) {
            int wv = wtot[lane];
            int ws_ = wv;
            #pragma unroll
            for (int off = 1; off < 16; off <<= 1) {
                int t = __shfl_up(ws_, off, 64);
                if (lane >= off) ws_ += t;
            }
            wtot[lane] = ws_ - wv;
        }
        __syncthreads();
        int excl = carry + wtot[wid] + (s - tsum);
        int4 o;
        o.x = excl; o.y = o.x + v.x; o.z = o.y + v.y; o.w = o.z + v.z;
        if (i4 + 3 < n) {
            *(int4*)(rp + i4) = o;
            *(int4*)(cursor + i4) = o;
        } else {
            if (i4 + 0 < n) { rp[i4 + 0] = o.x; cursor[i4 + 0] = o.x; }
            if (i4 + 1 < n) { rp[i4 + 1] = o.y; cursor[i4 + 1] = o.y; }
            if (i4 + 2 < n) { rp[i4 + 2] = o.z; cursor[i4 + 2] = o.z; }
            if (i4 + 3 < n) { rp[i4 + 3] = o.w; cursor[i4 + 3] = o.w; }
        }
        __syncthreads();
        if (tid == 1023) carry = o.w + v.w;
        __syncthreads();
    }
    if (tid == 0) rp[n] = carry;
}

__global__ void fill_kernel(const int* __restrict__ src, const int* __restrict__ dst,
                            int* __restrict__ cursor, int* __restrict__ col, int nE) {
    int e = blockIdx.x * blockDim.x + threadIdx.x;
    if (e < nE) {
        int d = dst[e];
        int p = atomicAdd(&cursor[d], 1);
        col[p] = src[e];
    }
}

// ---- GEMM1 (t = xb @ W1^T, 128x128 tiles) merged with degree histogram ----
// blocks [0, gemmBlocks): gemm tile b -> m0=(b>>2)*128, n0=(b&3)*128 (N=K=512)
// blocks [gemmBlocks, ...): grid-stride degree atomics (hidden under MFMA)
__global__ __launch_bounds__(256) void gemm1_hist(
        const __bf16* __restrict__ A, const __bf16* __restrict__ B,
        __bf16* __restrict__ Cout, int M, int gemmBlocks,
        const int* __restrict__ dst, int* __restrict__ deg, int nE) {
    constexpr int BM = 128, BN = 128, BK = 32;
    constexpr int MI = 4, NI = 4;     // WR=WC=2 -> 64x64 wave tile
    constexpr int CPA = 2, CPB = 2;

    if (blockIdx.x >= gemmBlocks) {
        int base = (blockIdx.x - gemmBlocks) * 256 + threadIdx.x;
        int stride = (gridDim.x - gemmBlocks) * 256;
        for (int e = base; e < nE; e += stride) atomicAdd(&deg[dst[e]], 1);
        return;
    }

    __shared__ __bf16 As[4 * BM * 8];
    __shared__ __bf16 Bs[4 * BN * 8];

    const int tid = threadIdx.x;
    const int w = tid >> 6, lane = tid & 63;
    const int wrow = w >> 1, wcol = w & 1;
    const int m0 = (blockIdx.x >> 2) * BM, n0 = (blockIdx.x & 3) * BN;
    const int quad = lane >> 4, l15 = lane & 15;

    floatx4 acc[MI][NI] = {};

    for (int k0 = 0; k0 < D; k0 += BK) {
        #pragma unroll
        for (int c = 0; c < CPA; ++c) {
            int ca = w * CPA + c;
            int kq = ca / CPA;
            int row = m0 + (ca % CPA) * 64 + lane;
            if (row > M - 1) row = M - 1;
            async_cp16(A + (size_t)row * D + k0 + kq * 8, &As[(size_t)ca * 512]);
        }
        #pragma unroll
        for (int c = 0; c < CPB; ++c) {
            int cb = w * CPB + c;
            int kq = cb / CPB;
            int nn = n0 + (cb % CPB) * 64 + lane;
            async_cp16(B + (size_t)nn * D + k0 + kq * 8, &Bs[(size_t)cb * 512]);
        }
        __syncthreads();

        bf16x8 af[MI], bfr[NI];
        #pragma unroll
        for (int mi = 0; mi < MI; ++mi)
            af[mi] = *(const bf16x8*)&As[(size_t)(quad * BM + wrow * 64 + mi * 16 + l15) * 8];
        #pragma unroll
        for (int nj = 0; nj < NI; ++nj)
            bfr[nj] = *(const bf16x8*)&Bs[(size_t)(quad * BN + wcol * 64 + nj * 16 + l15) * 8];
        #pragma unroll
        for (int mi = 0; mi < MI; ++mi)
            #pragma unroll
            for (int nj = 0; nj < NI; ++nj)
                acc[mi][nj] = __builtin_amdgcn_mfma_f32_16x16x32_bf16(
                    af[mi], bfr[nj], acc[mi][nj], 0, 0, 0);
        __syncthreads();
    }

    #pragma unroll
    for (int mi = 0; mi < MI; ++mi) {
        #pragma unroll
        for (int r = 0; r < 4; ++r) {
            int m = m0 + wrow * 64 + mi * 16 + quad * 4 + r;
            if (m < M) {
                #pragma unroll
                for (int nj = 0; nj < NI; ++nj) {
                    int n = n0 + wcol * 64 + nj * 16 + l15;
                    Cout[(size_t)m * D + n] = (__bf16)acc[mi][nj][r];
                }
            }
        }
    }
}

// ---- fused: h2-rows = relu(S t) gathered into LDS, u = h2 @ W2^T (bf16 out) ----
// 16 nodes/block, 4 waves; wave w owns output cols [w*16, w*16+16).
// LDS ~20 KB -> 8 blocks/CU -> 32 waves/CU for the latency-bound gather phase.
__global__ __launch_bounds__(256) void prop1_gemm2(
        const __bf16* __restrict__ t, const int* __restrict__ rp,
        const int* __restrict__ col, const __bf16* __restrict__ B,
        __bf16* __restrict__ u, int nN) {
    __shared__ __bf16 As[16 * 512];    // 16KB: granule P = r*64 + ((g+r)&63)
    __shared__ __bf16 Bs[4 * 64 * 8];  // 4KB chunk of W2: granule P = kq*64 + n

    const int tid = threadIdx.x;
    const int w = tid >> 6, lane = tid & 63;
    const int quad = lane >> 4, l15 = lane & 15;
    const int m0 = blockIdx.x * 16;

    // gather phase: wave w handles local rows w, w+4, w+8, w+12
    for (int r = w; r < 16; r += 4) {
        int n = m0 + r;
        float acc0[8] = {}, acc1[8] = {};
        if (n < nN) {
            int s0 = rp[n], s1 = rp[n + 1];
            int e = s0;
            for (; e + 4 <= s1; e += 4) {
                int sa = col[e], sb = col[e + 1], sc = col[e + 2], sd = col[e + 3];
                bf16x8 va = *(const bf16x8*)(t + (size_t)sa * D + lane * 8);
                bf16x8 vb = *(const bf16x8*)(t + (size_t)sb * D + lane * 8);
                bf16x8 vc = *(const bf16x8*)(t + (size_t)sc * D + lane * 8);
                bf16x8 vd = *(const bf16x8*)(t + (size_t)sd * D + lane * 8);
                #pragma unroll
                for (int i = 0; i < 8; ++i) {
                    acc0[i] += (float)va[i] + (float)vc[i];
                    acc1[i] += (float)vb[i] + (float)vd[i];
                }
            }
            for (; e < s1; ++e) {
                int sa = col[e];
                bf16x8 va = *(const bf16x8*)(t + (size_t)sa * D + lane * 8);
                #pragma unroll
                for (int i = 0; i < 8; ++i) acc0[i] += (float)va[i];
            }
        }
        bf16x8 o;
        #pragma unroll
        for (int i = 0; i < 8; ++i) o[i] = (__bf16)fmaxf(acc0[i] + acc1[i], 0.f);
        int P = r * 64 + ((lane + r) & 63);
        *(bf16x8*)&As[(size_t)P * 8] = o;
    }
    __syncthreads();

    // K-loop: stream W2 chunks, MFMA (M=16 tile; all waves read same A-frags)
    floatx4 acc = {};
    for (int k0 = 0; k0 < D; k0 += 32) {
        async_cp16(B + (size_t)lane * D + k0 + w * 8, &Bs[(size_t)w * 512]);
        __syncthreads();
        int g = (k0 >> 3) + quad;
        bf16x8 af = *(const bf16x8*)&As[(size_t)(l15 * 64 + ((g + l15) & 63)) * 8];
        bf16x8 bfr = *(const bf16x8*)&Bs[(size_t)(quad * 64 + w * 16 + l15) * 8];
        acc = __builtin_amdgcn_mfma_f32_16x16x32_bf16(af, bfr, acc, 0, 0, 0);
        __syncthreads();
    }

    // write u rows (bf16): row = quad*4 + r, col = w*16 + l15
    #pragma unroll
    for (int r = 0; r < 4; ++r) {
        int m = m0 + quad * 4 + r;
        if (m < nN)
            u[(size_t)m * DOUT + w * 16 + l15] = (__bf16)acc[r];
    }
}

// ---- propagate 64-wide + log_softmax fused: wave per node, lane = output col ----
__global__ __launch_bounds__(256) void prop2_lsm(const __bf16* __restrict__ u,
        const int* __restrict__ rp, const int* __restrict__ col,
        float* __restrict__ out, int nN) {
    int n = blockIdx.x * 4 + (threadIdx.x >> 6);
    if (n >= nN) return;
    int lane = threadIdx.x & 63;
    int s0 = rp[n], s1 = rp[n + 1];
    float a0 = 0.f, a1 = 0.f, a2 = 0.f, a3 = 0.f;
    int e = s0;
    for (; e + 4 <= s1; e += 4) {
        int sa = col[e], sb = col[e + 1], sc = col[e + 2], sd = col[e + 3];
        a0 += (float)u[(size_t)sa * DOUT + lane];
        a1 += (float)u[(size_t)sb * DOUT + lane];
        a2 += (float)u[(size_t)sc * DOUT + lane];
        a3 += (float)u[(size_t)sd * DOUT + lane];
    }
    for (; e < s1; ++e) a0 += (float)u[(size_t)col[e] * DOUT + lane];
    float v = (a0 + a2) + (a1 + a3);
    float mx = v;
    #pragma unroll
    for (int off = 32; off >= 1; off >>= 1) mx = fmaxf(mx, __shfl_xor(mx, off, 64));
    float s = expf(v - mx);
    #pragma unroll
    for (int off = 32; off >= 1; off >>= 1) s += __shfl_xor(s, off, 64);
    out[(size_t)n * DOUT + lane] = v - mx - logf(s);
}

// ---------------- launch ----------------

extern "C" void kernel_launch(void* const* d_in, const int* in_sizes, int n_in,
                              void* d_out, int out_size, void* d_ws, size_t ws_size,
                              hipStream_t stream) {
    const float* x  = (const float*)d_in[0];
    const int*   ei = (const int*)d_in[1];
    const float* W1 = (const float*)d_in[2];
    const float* W2 = (const float*)d_in[3];
    float* out = (float*)d_out;

    const int N = in_sizes[0] / D;   // 20000
    const int E = in_sizes[1] / 2;   // 160000
    const int* src = ei;
    const int* dst = ei + E;

    size_t off = 0;
    auto alloc = [&](size_t bytes) -> void* {
        void* p = (char*)d_ws + off;
        off = (off + bytes + 255) & ~(size_t)255;
        return p;
    };
    int*    deg     = (int*)alloc(sizeof(int) * (size_t)N);
    int*    row_ptr = (int*)alloc(sizeof(int) * (size_t)(N + 1));
    int*    cursor  = (int*)alloc(sizeof(int) * (size_t)N);
    int*    col     = (int*)alloc(sizeof(int) * (size_t)E);
    __bf16* w1b     = (__bf16*)alloc(sizeof(__bf16) * (size_t)D * D);
    __bf16* w2b     = (__bf16*)alloc(sizeof(__bf16) * (size_t)DOUT * D);
    __bf16* xb      = (__bf16*)alloc(sizeof(__bf16) * (size_t)N * D);
    __bf16* t       = (__bf16*)alloc(sizeof(__bf16) * (size_t)N * D);    // x@W1^T
    __bf16* u       = (__bf16*)alloc(sizeof(__bf16) * (size_t)N * DOUT); // relu(S t)@W2^T

    const int zeroBlocks = (N + 1023) / 1024;
    const int xN8 = N * D / 8, w1N8 = D * D / 8, w2N8 = DOUT * D / 8;
    const int cvtBlocks = (xN8 + 255) / 256 + (w1N8 + 255) / 256 + (w2N8 + 255) / 256;

    // 1) prep: zero deg + bf16 conversions (all independent)
    prep_kernel<<<zeroBlocks + cvtBlocks, 256, 0, stream>>>(
        deg, N, zeroBlocks, x, xb, xN8, W1, w1b, w1N8, W2, w2b, w2N8);

    // 2) t = xb @ W1^T merged with degree histogram (hist hides under MFMA)
    const int gemmBlocks = ((N + 127) / 128) * 4;
    gemm1_hist<<<gemmBlocks + 64, 256, 0, stream>>>(
        xb, w1b, t, N, gemmBlocks, dst, deg, E);

    // 3) exclusive scan -> row_ptr, cursor
    exscan_kernel<<<1, 1024, 0, stream>>>(deg, row_ptr, cursor, N);
    // 4) CSR fill
    fill_kernel<<<(E + 255) / 256, 256, 0, stream>>>(src, dst, cursor, col, E);

    // 5) u = relu(S t) @ W2^T  (fused gather + small GEMM; h2 never materialized)
    prop1_gemm2<<<(N + 15) / 16, 256, 0, stream>>>(t, row_ptr, col, w2b, u, N);
    // 6) out = lsm(S u)
    prop2_lsm<<<(N + 3) / 4, 256, 0, stream>>>(u, row_ptr, col, out, N);
}